// Round 1
// baseline (308.644 us; speedup 1.0000x reference)
//
#include <hip/hip_runtime.h>

#define NB 32
#define NC 3
#define NK 64
#define KS 7
#define IH 224
#define IW 224
#define OH 218
#define OW 218

typedef float  f32x4 __attribute__((ext_vector_type(4)));
typedef short  s16x8 __attribute__((ext_vector_type(8)));

static __device__ __forceinline__ unsigned short f2bf(float f) {
  unsigned int u = __float_as_uint(f);
  u += 0x7FFFu + ((u >> 16) & 1u);
  return (unsigned short)(u >> 16);
}

// ---------------- prep kernels ----------------

// convert x -> bf16, s[b][h][w] = sum_c x^2
__global__ void k_prep_x(const float* __restrict__ x, unsigned short* __restrict__ xb,
                         float* __restrict__ s) {
  int n = blockIdx.x * 256 + threadIdx.x;            // NB*IH*IW
  if (n >= NB * IH * IW) return;
  int b = n / (IH * IW);
  int p = n - b * (IH * IW);
  float acc = 0.f;
#pragma unroll
  for (int c = 0; c < NC; ++c) {
    float v = x[(b * NC + c) * (IH * IW) + p];
    xb[(b * NC + c) * (IH * IW) + p] = f2bf(v);
    acc += v * v;
  }
  s[n] = acc;
}

// row box filter: t[b][h][ow] = sum_{j<7} s[b][h][ow+j]
__global__ void k_rowbox(const float* __restrict__ s, float* __restrict__ t) {
  int n = blockIdx.x * 256 + threadIdx.x;            // NB*IH*OW
  if (n >= NB * IH * OW) return;
  int b = n / (IH * OW);
  int r = n - b * (IH * OW);
  int h = r / OW;
  int ow = r - h * OW;
  const float* row = s + (b * IH + h) * IW + ow;
  float acc = 0.f;
#pragma unroll
  for (int j = 0; j < KS; ++j) acc += row[j];
  t[n] = acc;
}

// col box filter: x2[b][oh][ow] = sum_{i<7} t[b][oh+i][ow]
__global__ void k_colbox(const float* __restrict__ t, float* __restrict__ x2) {
  int n = blockIdx.x * 256 + threadIdx.x;            // NB*OH*OW
  if (n >= NB * OH * OW) return;
  int b = n / (OH * OW);
  int r = n - b * (OH * OW);
  int oh = r / OW;
  int ow = r - oh * OW;
  const float* col = t + (b * IH + oh) * OW + ow;
  float acc = 0.f;
#pragma unroll
  for (int i = 0; i < KS; ++i) acc += col[i * OW];
  x2[n] = acc;
}

// weights: WTg[j][k][ci(pad 40)] = bf16(memes[k][c][i][j]), ci = c*7+i (<21), zeros above
// m2inv[k] = 1 / sum(memes[k]^2)
__global__ void k_prep_w(const float* __restrict__ memes, unsigned short* __restrict__ WTg,
                         float* __restrict__ m2inv) {
  int k = threadIdx.x;
  if (k >= NK) return;
  const float* mk = memes + k * (NC * KS * KS);
  float m2 = 0.f;
  for (int c = 0; c < NC; ++c)
    for (int i = 0; i < KS; ++i)
      for (int j = 0; j < KS; ++j) {
        float v = mk[(c * KS + i) * KS + j];
        m2 += v * v;
        WTg[(j * NK + k) * 40 + (c * KS + i)] = f2bf(v);
      }
  for (int j = 0; j < KS; ++j)
    for (int ci = NC * KS; ci < 40; ++ci)
      WTg[(j * NK + k) * 40 + ci] = 0;
  m2inv[k] = 1.0f / m2;
}

// ---------------- main MFMA kernel ----------------
// block: 256 threads (4 waves). Tile: one (b, oh), 64 consecutive ow, all 64 k.
// GEMM per j-step (j=0..6): D[k][px] += WT[j][k][ci] * XT[px+j][ci], ci padded 21->32.
__global__ __launch_bounds__(256) void k_main(
    const unsigned short* __restrict__ xb, const float* __restrict__ x2g,
    const unsigned short* __restrict__ WTg, const float* __restrict__ m2inv,
    float* __restrict__ out) {
  __shared__ unsigned short WTl[KS * NK * 40];   // 35840 B, row stride 80 B
  __shared__ unsigned short XTl[72 * 40];        // 5760 B
  __shared__ float m2l[NK];

  const int tid  = threadIdx.x;
  const int w    = tid >> 6;        // wave 0..3
  const int lane = tid & 63;
  const int lg   = lane >> 4;       // 0..3
  const int lr   = lane & 15;

  const int ow0 = blockIdx.x * 64;
  const int oh  = blockIdx.y;
  const int b   = blockIdx.z;

  // stage WT: flat 16B copy (2240 uint4)
  {
    const uint4* src = (const uint4*)WTg;
    uint4* dst = (uint4*)WTl;
    for (int idx = tid; idx < 2240; idx += 256) dst[idx] = src[idx];
  }
  if (tid < NK) m2l[tid] = m2inv[tid];

  // stage XT[t][ci]: t = ow offset within tile (0..69), ci = c*7+i
  for (int ci = w; ci < NC * KS; ci += 4) {
    int c = ci / KS, i = ci - KS * c;
    const unsigned short* src = xb + ((b * NC + c) * IH + (oh + i)) * IW + ow0;
    XTl[lane * 40 + ci] = (ow0 + lane < IW) ? src[lane] : (unsigned short)0;
    if (lane < 6) {
      int t1 = 64 + lane;
      XTl[t1 * 40 + ci] = (ow0 + t1 < IW) ? src[t1] : (unsigned short)0;
    }
  }
  // zero pad ci 21..31 (must be finite: it feeds MFMA where A side is 0)
  for (int cz = NC * KS + w; cz < 32; cz += 4) {
    XTl[lane * 40 + cz] = 0;
    if (lane < 8) XTl[(64 + lane) * 40 + cz] = 0;
  }
  __syncthreads();

  const int n0 = w * 16;            // this wave's pixel group
  const int px = n0 + lr;
  if (ow0 + n0 >= OW) return;       // wave-uniform; whole wave has no valid output

  f32x4 acc0 = {0.f, 0.f, 0.f, 0.f};
  f32x4 acc1 = acc0, acc2 = acc0, acc3 = acc0;

#pragma unroll
  for (int j = 0; j < KS; ++j) {
    s16x8 bfrag = *(const s16x8*)&XTl[(px + j) * 40 + 8 * lg];
    s16x8 a0 = *(const s16x8*)&WTl[(j * NK +  0 + lr) * 40 + 8 * lg];
    s16x8 a1 = *(const s16x8*)&WTl[(j * NK + 16 + lr) * 40 + 8 * lg];
    s16x8 a2 = *(const s16x8*)&WTl[(j * NK + 32 + lr) * 40 + 8 * lg];
    s16x8 a3 = *(const s16x8*)&WTl[(j * NK + 48 + lr) * 40 + 8 * lg];
    acc0 = __builtin_amdgcn_mfma_f32_16x16x32_bf16(a0, bfrag, acc0, 0, 0, 0);
    acc1 = __builtin_amdgcn_mfma_f32_16x16x32_bf16(a1, bfrag, acc1, 0, 0, 0);
    acc2 = __builtin_amdgcn_mfma_f32_16x16x32_bf16(a2, bfrag, acc2, 0, 0, 0);
    acc3 = __builtin_amdgcn_mfma_f32_16x16x32_bf16(a3, bfrag, acc3, 0, 0, 0);
  }

  const int ow = ow0 + px;
  if (ow >= OW) return;             // per-lane store mask (MFMA already done)
  const float x2v = x2g[(b * OH + oh) * OW + ow];
  float* obase = out + ((size_t)(b * NK) * OH + oh) * OW + ow;

#pragma unroll
  for (int kg = 0; kg < 4; ++kg) {
    f32x4 a = (kg == 0) ? acc0 : (kg == 1) ? acc1 : (kg == 2) ? acc2 : acc3;
#pragma unroll
    for (int r = 0; r < 4; ++r) {
      int k = kg * 16 + 4 * lg + r;             // D row -> template index
      float val = (x2v - 2.0f * a[r]) * m2l[k] + 1.0f;
      obase[(size_t)k * (OH * OW)] = val;
    }
  }
}

// ---------------- launch ----------------
extern "C" void kernel_launch(void* const* d_in, const int* in_sizes, int n_in,
                              void* d_out, int out_size, void* d_ws, size_t ws_size,
                              hipStream_t stream) {
  const float* x     = (const float*)d_in[0];   // [32,3,224,224]
  const float* memes = (const float*)d_in[1];   // [64,3,7,7]
  float* out = (float*)d_out;                   // [32,64,218,218]

  char* ws = (char*)d_ws;
  unsigned short* xb  = (unsigned short*)(ws);                       // 9,633,792 B
  float* s            = (float*)(ws + 9633792);                      // 6,422,528 B
  float* t            = (float*)(ws + 16056320);                     // 6,250,496 B
  float* x2           = (float*)(ws + 22306816);                     // 6,083,072 B
  unsigned short* WTg = (unsigned short*)(ws + 28389888);            // 35,840 B
  float* m2inv        = (float*)(ws + 28425728);                     // 256 B

  (void)in_sizes; (void)n_in; (void)out_size; (void)ws_size;

  k_prep_x<<<(NB * IH * IW + 255) / 256, 256, 0, stream>>>(x, xb, s);
  k_rowbox<<<(NB * IH * OW + 255) / 256, 256, 0, stream>>>(s, t);
  k_colbox<<<(NB * OH * OW + 255) / 256, 256, 0, stream>>>(t, x2);
  k_prep_w<<<1, 64, 0, stream>>>(memes, WTg, m2inv);

  dim3 grid((OW + 63) / 64, OH, NB);
  k_main<<<grid, 256, 0, stream>>>(xb, x2, WTg, m2inv, out);
}

// Round 2
// 189.037 us; speedup vs baseline: 1.6327x; 1.6327x over previous
//
#include <hip/hip_runtime.h>

#define NB 32
#define NC 3
#define NK 64
#define KS 7
#define IH 224
#define IW 224
#define OH 218
#define OW 218
#define ROWS 4
#define OHW (OH * OW)

typedef float  f32x4 __attribute__((ext_vector_type(4)));
typedef short  s16x8 __attribute__((ext_vector_type(8)));

static __device__ __forceinline__ unsigned short f2bf(float f) {
  unsigned int u = __float_as_uint(f);
  u += 0x7FFFu + ((u >> 16) & 1u);
  return (unsigned short)(u >> 16);
}

// XOR block-swizzle: u16 index within a 32-u16 (64 B) row. Row r, element ci.
// 16B-block index gets XORed with (r>>1)&3 -> 16 lanes reading consecutive rows
// at the same ci-block spread across banks (2-way max = free).
static __device__ __forceinline__ int swz(int r, int ci) {
  return (((ci >> 3) ^ ((r >> 1) & 3)) << 3) | (ci & 7);
}

// ---------------- prep kernels ----------------

__global__ void k_prep_x(const float* __restrict__ x, unsigned short* __restrict__ xb,
                         float* __restrict__ s) {
  int n = blockIdx.x * 256 + threadIdx.x;            // NB*IH*IW
  if (n >= NB * IH * IW) return;
  int b = n / (IH * IW);
  int p = n - b * (IH * IW);
  float acc = 0.f;
#pragma unroll
  for (int c = 0; c < NC; ++c) {
    float v = x[(b * NC + c) * (IH * IW) + p];
    xb[(b * NC + c) * (IH * IW) + p] = f2bf(v);
    acc += v * v;
  }
  s[n] = acc;
}

__global__ void k_rowbox(const float* __restrict__ s, float* __restrict__ t) {
  int n = blockIdx.x * 256 + threadIdx.x;            // NB*IH*OW
  if (n >= NB * IH * OW) return;
  int b = n / (IH * OW);
  int r = n - b * (IH * OW);
  int h = r / OW;
  int ow = r - h * OW;
  const float* row = s + (b * IH + h) * IW + ow;
  float acc = 0.f;
#pragma unroll
  for (int j = 0; j < KS; ++j) acc += row[j];
  t[n] = acc;
}

__global__ void k_colbox(const float* __restrict__ t, float* __restrict__ x2) {
  int n = blockIdx.x * 256 + threadIdx.x;            // NB*OH*OW
  if (n >= NB * OH * OW) return;
  int b = n / (OH * OW);
  int r = n - b * (OH * OW);
  int oh = r / OW;
  int ow = r - oh * OW;
  const float* col = t + (b * IH + oh) * OW + ow;
  float acc = 0.f;
#pragma unroll
  for (int i = 0; i < KS; ++i) acc += col[i * OW];
  x2[n] = acc;
}

// WTg[row=j*64+k][ci'(swizzled, 32)] = bf16(memes[k][c][i][j]); zeros at ci>=21.
__global__ void k_prep_w(const float* __restrict__ memes, unsigned short* __restrict__ WTg,
                         float* __restrict__ m2inv) {
  int k = threadIdx.x;
  if (k >= NK) return;
  const float* mk = memes + k * (NC * KS * KS);
  float m2 = 0.f;
  for (int c = 0; c < NC; ++c)
    for (int i = 0; i < KS; ++i)
      for (int j = 0; j < KS; ++j) {
        float v = mk[(c * KS + i) * KS + j];
        m2 += v * v;
        int row = j * NK + k;
        WTg[row * 32 + swz(row, c * KS + i)] = f2bf(v);
      }
  for (int j = 0; j < KS; ++j) {
    int row = j * NK + k;
    for (int ci = NC * KS; ci < 32; ++ci)
      WTg[row * 32 + swz(row, ci)] = 0;
  }
  m2inv[k] = 1.0f / m2;
}

// ---------------- staging helpers (issue-early / write-late) ----------------
// One output row's X tile: 21 ci x 70 t. 1470 elems over 256 threads * 6.
static __device__ __forceinline__ void xt_issue(unsigned short v[6],
    const unsigned short* __restrict__ xb, int b, int oh, int ow0, int tid) {
#pragma unroll
  for (int m = 0; m < 6; ++m) {
    int idx = tid + 256 * m;
    unsigned short val = 0;
    if (idx < 21 * 70) {
      int ci = idx / 70;
      int t  = idx - ci * 70;
      int c  = ci / 7;
      int i  = ci - 7 * c;
      int ow = ow0 + t;
      if (ow < IW) val = xb[((b * NC + c) * IH + (oh + i)) * IW + ow];
    }
    v[m] = val;
  }
}

static __device__ __forceinline__ void xt_write(unsigned short* XT,
    const unsigned short v[6], int tid) {
#pragma unroll
  for (int m = 0; m < 6; ++m) {
    int idx = tid + 256 * m;
    if (idx < 21 * 70) {
      int ci = idx / 70;
      int t  = idx - ci * 70;
      XT[t * 32 + swz(t, ci)] = v[m];
    }
  }
}

// ---------------- main MFMA kernel ----------------
// Block: 256 threads (4 waves). Tile: one b, ROWS oh rows, 64 ow, all 64 k.
// Per j-step (j=0..6): D[k][px] += WT[j][k][ci] * XT[px+j][ci]  (K = 32, zero-padded).
__global__ __launch_bounds__(256, 4) void k_main(
    const unsigned short* __restrict__ xb, const float* __restrict__ x2g,
    const unsigned short* __restrict__ WTg, const float* __restrict__ m2inv,
    float* __restrict__ out) {
  __shared__ __align__(16) unsigned short WTl[KS * NK * 32];   // 28672 B
  __shared__ __align__(16) unsigned short XTl[2][72 * 32];     // 9216 B
  __shared__ float m2l[NK];

  const int tid  = threadIdx.x;
  const int w    = tid >> 6;
  const int lane = tid & 63;
  const int lg   = lane >> 4;
  const int lr   = lane & 15;

  const int ow0 = blockIdx.x * 64;
  const int oh0 = blockIdx.y * ROWS;
  const int b   = blockIdx.z;

  // WT: exact linear copy global->LDS, 28 chunks of 1024 B, async width-16.
  for (int ch = w; ch < 28; ch += 4) {
    const unsigned short* g = WTg + ch * 512 + lane * 8;
    unsigned short* l = WTl + ch * 512;
    __builtin_amdgcn_global_load_lds((const __attribute__((address_space(1))) void*)g,
                                     (__attribute__((address_space(3))) void*)l, 16, 0, 0);
  }
  if (tid < NK) m2l[tid] = m2inv[tid];

  // zero ci pads 21..31 for both XT buffers (never overwritten; must be finite)
  for (int idx = tid; idx < 2 * 72 * 11; idx += 256) {
    int bb = idx / (72 * 11);
    int rm = idx - bb * (72 * 11);
    int t  = rm / 11;
    int cz = 21 + (rm - t * 11);
    XTl[bb][t * 32 + swz(t, cz)] = 0;
  }

  unsigned short v0[6];
  xt_issue(v0, xb, b, oh0, ow0, tid);
  xt_write(&XTl[0][0], v0, tid);
  __syncthreads();                  // also drains WT global_load_lds (vmcnt)

  const int px  = w * 16 + lr;
  const int swa = (lr >> 1) & 3;    // A-row = j*64+q*16+lr -> (row>>1)&3 == (lr>>1)&3

#pragma unroll 1
  for (int r = 0; r < ROWS; ++r) {
    const int oh = oh0 + r;
    if (oh >= OH) break;            // block-uniform (barrier-safe)
    const bool havenext = (r + 1 < ROWS) && (oh + 1 < OH);

    unsigned short vn[6];
    if (havenext) xt_issue(vn, xb, b, oh + 1, ow0, tid);   // loads in flight over MFMAs

    const unsigned short* XT = &XTl[r & 1][0];
    f32x4 acc0 = {0.f, 0.f, 0.f, 0.f};
    f32x4 acc1 = acc0, acc2 = acc0, acc3 = acc0;

#pragma unroll
    for (int j = 0; j < KS; ++j) {
      const int t = px + j;
      s16x8 bf_ = *(const s16x8*)&XT[t * 32 + ((lg ^ ((t >> 1) & 3)) << 3)];
      const unsigned short* ab = WTl + j * (NK * 32) + lr * 32 + ((lg ^ swa) << 3);
      s16x8 a0 = *(const s16x8*)&ab[0];
      s16x8 a1 = *(const s16x8*)&ab[16 * 32];
      s16x8 a2 = *(const s16x8*)&ab[32 * 32];
      s16x8 a3 = *(const s16x8*)&ab[48 * 32];
      acc0 = __builtin_amdgcn_mfma_f32_16x16x32_bf16(a0, bf_, acc0, 0, 0, 0);
      acc1 = __builtin_amdgcn_mfma_f32_16x16x32_bf16(a1, bf_, acc1, 0, 0, 0);
      acc2 = __builtin_amdgcn_mfma_f32_16x16x32_bf16(a2, bf_, acc2, 0, 0, 0);
      acc3 = __builtin_amdgcn_mfma_f32_16x16x32_bf16(a3, bf_, acc3, 0, 0, 0);
    }

    const int ow = ow0 + px;
    if (ow < OW) {
      const float x2v = x2g[(b * OH + oh) * OW + ow];
      float* obase = out + ((size_t)(b * NK) * OH + oh) * OW + ow;
#pragma unroll
      for (int rr = 0; rr < 4; ++rr) {
        int k0 = 4 * lg + rr;
        obase[(size_t)(k0)      * OHW] = (x2v - 2.0f * acc0[rr]) * m2l[k0]      + 1.0f;
        obase[(size_t)(k0 + 16) * OHW] = (x2v - 2.0f * acc1[rr]) * m2l[k0 + 16] + 1.0f;
        obase[(size_t)(k0 + 32) * OHW] = (x2v - 2.0f * acc2[rr]) * m2l[k0 + 32] + 1.0f;
        obase[(size_t)(k0 + 48) * OHW] = (x2v - 2.0f * acc3[rr]) * m2l[k0 + 48] + 1.0f;
      }
    }

    if (havenext) xt_write(&XTl[(r + 1) & 1][0], vn, tid);  // write-late
    __syncthreads();
  }
}

// ---------------- launch ----------------
extern "C" void kernel_launch(void* const* d_in, const int* in_sizes, int n_in,
                              void* d_out, int out_size, void* d_ws, size_t ws_size,
                              hipStream_t stream) {
  const float* x     = (const float*)d_in[0];   // [32,3,224,224]
  const float* memes = (const float*)d_in[1];   // [64,3,7,7]
  float* out = (float*)d_out;                   // [32,64,218,218]

  char* ws = (char*)d_ws;
  unsigned short* xb  = (unsigned short*)(ws);                       // 9,633,792 B
  float* s            = (float*)(ws + 9633792);                      // 6,422,528 B
  float* t            = (float*)(ws + 16056320);                     // 6,250,496 B
  float* x2           = (float*)(ws + 22306816);                     // 6,083,072 B
  unsigned short* WTg = (unsigned short*)(ws + 28389888);            // 28,672 B
  float* m2inv        = (float*)(ws + 28418560);                     // 256 B

  (void)in_sizes; (void)n_in; (void)out_size; (void)ws_size;

  k_prep_x<<<(NB * IH * IW + 255) / 256, 256, 0, stream>>>(x, xb, s);
  k_rowbox<<<(NB * IH * OW + 255) / 256, 256, 0, stream>>>(s, t);
  k_colbox<<<(NB * OH * OW + 255) / 256, 256, 0, stream>>>(t, x2);
  k_prep_w<<<1, 64, 0, stream>>>(memes, WTg, m2inv);

  dim3 grid((OW + 63) / 64, (OH + ROWS - 1) / ROWS, NB);
  k_main<<<grid, 256, 0, stream>>>(xb, x2, WTg, m2inv, out);
}